// Round 15
// baseline (205.977 us; speedup 1.0000x reference)
//
#include <hip/hip_runtime.h>

// FWHT of 2^26 fp32, two passes, bf16 intermediate, col-par interleaved ws.
//   View: data[2048 rows][32768 cols] (row = bits 15..25, col = bits 0..14).
//   ws (bf16): ushort ws[1024 cb][1024 rp][32 col][2 par]  (128 MB).
//   Pass 1 (fwht_low15_pair2): R14-proven, byte-identical. Block = rowpair,
//     512 threads; row A bf16 stashed in 2nd 64 KB LDS region; uint4 writes
//     = full 128 B lines single-wave.
//   Pass 2 (fwht_high11_cb16): NEW — 512-thread blocks, 16 cols each
//     (2 blocks/CU: ~105 VGPR x 4 waves/SIMD = 420 <= 512; LDS 66 KB x 2
//     = 132 <= 160 KB) so ws loads of one block overlap the VALU ladder of
//     the other. Padded LDS rows (528 ~= 16 mod 32 -> 2-way = free).
//     XCD-pairing swizzle co-locates sibling 16-col blocks (shared ws/out
//     lines). 64 B sector NT stores.
// Every global bit butterflied exactly once; stages commute == reference.
// Error: one bf16 RNE round of mid values -> absmax 256 (measured R8-R14),
// threshold 947. Fallback to all-fp32 2-pass path (R6) if ws too small.

typedef float nvf4 __attribute__((ext_vector_type(4)));

__device__ __forceinline__ float4 add4(float4 a, float4 b) {
    return make_float4(a.x + b.x, a.y + b.y, a.z + b.z, a.w + b.w);
}
__device__ __forceinline__ float4 sub4(float4 a, float4 b) {
    return make_float4(a.x - b.x, a.y - b.y, a.z - b.z, a.w - b.w);
}
__device__ __forceinline__ int SWZ(int q) { return q ^ ((q >> 3) & 7); }

__device__ __forceinline__ unsigned int bfp(float x) {   // fp32 -> bf16 RNE
    unsigned int u = __builtin_bit_cast(unsigned int, x);
    return (u + 0x7fffu + ((u >> 16) & 1u)) >> 16;
}
__device__ __forceinline__ float bf2f(unsigned int h) {  // low16 -> fp32
    unsigned int u = h << 16;
    return __builtin_bit_cast(float, u);
}

__device__ __forceinline__ void lad3(float4* u) {
    #pragma unroll
    for (int h = 1; h < 8; h <<= 1) {
        #pragma unroll
        for (int i = 0; i < 8; i += 2 * h) {
            #pragma unroll
            for (int k = 0; k < h; ++k) {
                float4 a = u[i + k], b = u[i + k + h];
                u[i + k] = add4(a, b);
                u[i + k + h] = sub4(a, b);
            }
        }
    }
}

// ---------------- Pass 1: bits 0..14, one ROWPAIR per 512-thread block ------
__global__ __launch_bounds__(512) void fwht_low15_pair2(
        const float* __restrict__ in, uint4* __restrict__ ws4) {
    __shared__ float4 lds4[4096];                    // 64 KB exchange region
    __shared__ uint2 stash[8192];                    // 64 KB row-A bf16 stash
    const int t = threadIdx.x;                       // 0..511
    const int rp = blockIdx.x;                       // rowpair 0..1023

    #pragma unroll
    for (int rr = 0; rr < 2; ++rr) {
        const nvf4* in4 =
            reinterpret_cast<const nvf4*>(in) + ((size_t)(2 * rp + rr) << 13);

        float4 v[16];
        #pragma unroll
        for (int k = 0; k < 16; ++k) {
            nvf4 xv = __builtin_nontemporal_load(in4 + t + 512 * k);
            float a0 = xv[0] + xv[1], a1 = xv[0] - xv[1];
            float a2 = xv[2] + xv[3], a3 = xv[2] - xv[3];
            v[k] = make_float4(a0 + a2, a1 + a3, a0 - a2, a1 - a3);
        }
        // k-ladder: quad bits 9..12 = float bits 11..14
        #pragma unroll
        for (int h = 1; h < 16; h <<= 1) {
            #pragma unroll
            for (int i = 0; i < 16; i += 2 * h) {
                #pragma unroll
                for (int k = 0; k < h; ++k) {
                    float4 a = v[i + k], b = v[i + k + h];
                    v[i + k] = add4(a, b);
                    v[i + k + h] = sub4(a, b);
                }
            }
        }

        #pragma unroll
        for (int hf = 0; hf < 2; ++hf) {
            float4* u = v + hf * 8;
            if (rr + hf) __syncthreads();            // prior ExC reads done
            #pragma unroll
            for (int k2 = 0; k2 < 8; ++k2)
                lds4[SWZ((k2 << 9) | t)] = u[k2];
            __syncthreads();

            // Exchange A: float bits 2..4
            #pragma unroll
            for (int j = 0; j < 8; ++j) u[j] = lds4[SWZ((t << 3) | j)];
            lad3(u);
            #pragma unroll
            for (int j = 0; j < 8; ++j) lds4[SWZ((t << 3) | j)] = u[j];
            __syncthreads();

            // Exchange B: float bits 5..7
            const int bB = ((t >> 3) << 6) | (t & 7);
            #pragma unroll
            for (int j = 0; j < 8; ++j) u[j] = lds4[SWZ(bB | (j << 3))];
            lad3(u);
            #pragma unroll
            for (int j = 0; j < 8; ++j) lds4[SWZ(bB | (j << 3))] = u[j];
            __syncthreads();

            // Exchange C: float bits 8..10, then pack bf16
            const int bC = ((t >> 6) << 9) | (t & 63);
            #pragma unroll
            for (int j = 0; j < 8; ++j) u[j] = lds4[SWZ(bC | (j << 6))];
            lad3(u);

            if (rr == 0) {
                #pragma unroll
                for (int j = 0; j < 8; ++j) {
                    uint2 pk;
                    pk.x = bfp(u[j].x) | (bfp(u[j].y) << 16);
                    pk.y = bfp(u[j].z) | (bfp(u[j].w) << 16);
                    stash[(hf * 8 + j) * 512 + t] = pk;
                }
            } else {
                #pragma unroll
                for (int j = 0; j < 8; ++j) {
                    uint2 pb;
                    pb.x = bfp(u[j].x) | (bfp(u[j].y) << 16);
                    pb.y = bfp(u[j].z) | (bfp(u[j].w) << 16);
                    uint2 pa = stash[(hf * 8 + j) * 512 + t];
                    uint4 o;                          // c0A c0B c1A c1B ...
                    o.x = (pa.x & 0xffffu) | (pb.x << 16);
                    o.y = (pa.x >> 16) | (pb.x & 0xffff0000u);
                    o.z = (pa.y & 0xffffu) | (pb.y << 16);
                    o.w = (pa.y >> 16) | (pb.y & 0xffff0000u);
                    const int q = (hf << 12) | bC | (j << 6);   // quad in row
                    ws4[(size_t)(q >> 3) * 8192 + rp * 8 + (q & 7)] = o;
                }
            }
        }
    }
}

// ---------------- Pass 2: bits 15..25, 16 cols per 512-thread block ---------
__global__ __launch_bounds__(512) void fwht_high11_cb16(
        const unsigned int* __restrict__ ws32, float* __restrict__ out) {
    __shared__ float lds[16896];                     // 32 rows x 528 (padded)
    const int t = threadIdx.x;
    const int c = t & 15;                            // col within 16-col block
    const int g = t >> 4;                            // 0..31
    // XCD-pairing swizzle (bijective, 2048 = 8*256): sibling 16-col blocks
    // (sharing ws/output 128 B lines) land on the same XCD, dispatch-adjacent.
    const int cbs = ((blockIdx.x & 7) << 8) | (blockIdx.x >> 3);   // 0..2047
    const unsigned int* wsb = ws32 + (size_t)(cbs >> 1) * 32768 + (cbs & 1) * 16;
    const size_t colg = (size_t)cbs * 16 + c;        // global column

    // v[2*jp+p] = bf16(rowpair g+32*jp, parity p, col colg)
    float v[64];
    #pragma unroll
    for (int jp = 0; jp < 32; ++jp) {
        unsigned int u = wsb[(g + 32 * jp) * 32 + c];
        v[2 * jp]     = bf2f(u & 0xffffu);
        v[2 * jp + 1] = bf2f(u >> 16);
    }

    // Phase A: 6-bit ladder (bit0 = parity = global bit 15, bits 1..5 = 21..25)
    #pragma unroll
    for (int h = 1; h < 64; h <<= 1) {
        #pragma unroll
        for (int i = 0; i < 64; i += 2 * h) {
            #pragma unroll
            for (int k = 0; k < h; ++k) {
                float a = v[i + k], b = v[i + k + h];
                v[i + k] = a + b;
                v[i + k + h] = a - b;
            }
        }
    }

    // Transpose chunks; phase B: 5-bit ladder over s (global bits 16..20)
    #pragma unroll
    for (int m = 0; m < 2; ++m) {
        if (m) __syncthreads();
        #pragma unroll
        for (int jj = 0; jj < 32; ++jj)
            lds[jj * 528 + g * 16 + c] = v[32 * m + jj];   // 2-way, free
        __syncthreads();

        float w[32];
        #pragma unroll
        for (int s = 0; s < 32; ++s)
            w[s] = lds[g * 528 + s * 16 + c];              // 2-way, free
        #pragma unroll
        for (int h = 1; h < 32; h <<= 1) {
            #pragma unroll
            for (int i = 0; i < 32; i += 2 * h) {
                #pragma unroll
                for (int k = 0; k < h; ++k) {
                    float a = w[i + k], b = w[i + k + h];
                    w[i + k] = a + b;
                    w[i + k + h] = a - b;
                }
            }
        }
        const int rbase = 1024 * m + 32 * (g & ~1) + (g & 1);
        #pragma unroll
        for (int s = 0; s < 32; ++s)
            __builtin_nontemporal_store(
                w[s], &out[((size_t)(rbase + 2 * s) << 15) + colg]);
    }
}

// ---------------- Fallback: proven all-fp32 2-pass path (R6) ----------------
__global__ __launch_bounds__(512) void fwht_low15_f32(const float* __restrict__ in,
                                                      float* __restrict__ out) {
    __shared__ float4 lds4[4096];
    const int t = threadIdx.x;
    const size_t base4 = (size_t)blockIdx.x * 8192;
    const nvf4* in4 = reinterpret_cast<const nvf4*>(in) + base4;
    float4* out4 = reinterpret_cast<float4*>(out) + base4;
    float4 v[16];
    #pragma unroll
    for (int k = 0; k < 16; ++k) {
        nvf4 xv = __builtin_nontemporal_load(in4 + t + 512 * k);
        float a0 = xv[0] + xv[1], a1 = xv[0] - xv[1];
        float a2 = xv[2] + xv[3], a3 = xv[2] - xv[3];
        v[k] = make_float4(a0 + a2, a1 + a3, a0 - a2, a1 - a3);
    }
    #pragma unroll
    for (int h = 1; h < 16; h <<= 1) {
        #pragma unroll
        for (int i = 0; i < 16; i += 2 * h) {
            #pragma unroll
            for (int k = 0; k < h; ++k) {
                float4 a = v[i + k], b = v[i + k + h];
                v[i + k] = add4(a, b);
                v[i + k + h] = sub4(a, b);
            }
        }
    }
    #pragma unroll
    for (int hf = 0; hf < 2; ++hf) {
        float4* u = v + hf * 8;
        if (hf) __syncthreads();
        #pragma unroll
        for (int k2 = 0; k2 < 8; ++k2) lds4[SWZ((k2 << 9) | t)] = u[k2];
        __syncthreads();
        #pragma unroll
        for (int j = 0; j < 8; ++j) u[j] = lds4[SWZ((t << 3) | j)];
        lad3(u);
        #pragma unroll
        for (int j = 0; j < 8; ++j) lds4[SWZ((t << 3) | j)] = u[j];
        __syncthreads();
        const int bB = ((t >> 3) << 6) | (t & 7);
        #pragma unroll
        for (int j = 0; j < 8; ++j) u[j] = lds4[SWZ(bB | (j << 3))];
        lad3(u);
        #pragma unroll
        for (int j = 0; j < 8; ++j) lds4[SWZ(bB | (j << 3))] = u[j];
        __syncthreads();
        const int bC = ((t >> 6) << 9) | (t & 63);
        #pragma unroll
        for (int j = 0; j < 8; ++j) u[j] = lds4[SWZ(bC | (j << 6))];
        lad3(u);
        #pragma unroll
        for (int j = 0; j < 8; ++j) out4[(hf << 12) | bC | (j << 6)] = u[j];
    }
}

__global__ __launch_bounds__(1024) void fwht_high11_f32(float* __restrict__ data) {
    __shared__ float lds[32768];
    const int t = threadIdx.x;
    const int c = t & 31;
    const int g = t >> 5;
    const size_t col = (size_t)blockIdx.x * 32 + c;
    float v[64];
    #pragma unroll
    for (int j = 0; j < 64; ++j)
        v[j] = data[((size_t)(g + 32 * j) << 15) + col];
    #pragma unroll
    for (int h = 1; h < 64; h <<= 1) {
        #pragma unroll
        for (int i = 0; i < 64; i += 2 * h) {
            #pragma unroll
            for (int k = 0; k < h; ++k) {
                float a = v[i + k], b = v[i + k + h];
                v[i + k] = a + b;
                v[i + k + h] = a - b;
            }
        }
    }
    #pragma unroll
    for (int m = 0; m < 2; ++m) {
        if (m) __syncthreads();
        #pragma unroll
        for (int jj = 0; jj < 32; ++jj)
            lds[jj * 1024 + g * 32 + c] = v[32 * m + jj];
        __syncthreads();
        float w[32];
        #pragma unroll
        for (int s = 0; s < 32; ++s) w[s] = lds[g * 1024 + s * 32 + c];
        #pragma unroll
        for (int h = 1; h < 32; h <<= 1) {
            #pragma unroll
            for (int i = 0; i < 32; i += 2 * h) {
                #pragma unroll
                for (int k = 0; k < h; ++k) {
                    float a = w[i + k], b = w[i + k + h];
                    w[i + k] = a + b;
                    w[i + k + h] = a - b;
                }
            }
        }
        const int rowbase = 32 * (32 * m + g);
        #pragma unroll
        for (int s = 0; s < 32; ++s)
            data[((size_t)(rowbase + s) << 15) + col] = w[s];
    }
}

extern "C" void kernel_launch(void* const* d_in, const int* in_sizes, int n_in,
                              void* d_out, int out_size, void* d_ws, size_t ws_size,
                              hipStream_t stream) {
    const float* x = (const float*)d_in[0];
    float* out = (float*)d_out;
    const size_t need = (size_t)1 << 27;             // 128 MB bf16 intermediate
    if (ws_size >= need && d_ws != nullptr) {
        fwht_low15_pair2<<<1024, 512, 0, stream>>>(x, (uint4*)d_ws);
        fwht_high11_cb16<<<2048, 512, 0, stream>>>((const unsigned int*)d_ws, out);
    } else {
        fwht_low15_f32<<<2048, 512, 0, stream>>>(x, out);
        fwht_high11_f32<<<1024, 1024, 0, stream>>>(out);
    }
}

// Round 16
// 174.708 us; speedup vs baseline: 1.1790x; 1.1790x over previous
//
#include <hip/hip_runtime.h>

// FWHT of 2^26 fp32, two passes, bf16 intermediate, col-par interleaved ws.
// == R14 configuration (best measured: 175.5 us) ==
//   View: data[2048 rows][32768 cols] (row = bits 15..25, col = bits 0..14).
//   ws (bf16): ushort ws[1024 cb][1024 rp][32 col][2 par]  (128 MB).
//   Pass 1 (fwht_low15_pair2): block = rowpair, 512 threads, rows sequential;
//     row A bf16 stashed in 2nd 64 KB LDS region; uint4 writes = full 128 B
//     lines single-wave. Per row: regs bits 0,1,11..14; 64 KB LDS exchanges
//     bits 2..10 (XOR-swizzled, conflict-free).
//   Pass 2 (fwht_high11_cb): 1024 threads, 32 cols, 128 KB contiguous ws
//     input per block; phase A = 6-bit ladder {bit15, 21..25}; 128 KB LDS
//     transpose (2 chunks); phase B = 5-bit ladder (16..20); fp32 NT stores
//     on FULL 128 B lines only.
// Ledger (measured): 3->2 passes +bf16+contig-P2 = win; XCD swizzle = +6.5us;
// NT-store policy = neutral; P1 full-line = neutral; P2 16-col/2-blk = -30us
// (64 B granularity beats occupancy). absmax 256 << 947.
// Fallback to all-fp32 2-pass path (R6) if ws too small.

typedef float nvf4 __attribute__((ext_vector_type(4)));

__device__ __forceinline__ float4 add4(float4 a, float4 b) {
    return make_float4(a.x + b.x, a.y + b.y, a.z + b.z, a.w + b.w);
}
__device__ __forceinline__ float4 sub4(float4 a, float4 b) {
    return make_float4(a.x - b.x, a.y - b.y, a.z - b.z, a.w - b.w);
}
__device__ __forceinline__ int SWZ(int q) { return q ^ ((q >> 3) & 7); }

__device__ __forceinline__ unsigned int bfp(float x) {   // fp32 -> bf16 RNE
    unsigned int u = __builtin_bit_cast(unsigned int, x);
    return (u + 0x7fffu + ((u >> 16) & 1u)) >> 16;
}
__device__ __forceinline__ float bf2f(unsigned int h) {  // low16 -> fp32
    unsigned int u = h << 16;
    return __builtin_bit_cast(float, u);
}

__device__ __forceinline__ void lad3(float4* u) {
    #pragma unroll
    for (int h = 1; h < 8; h <<= 1) {
        #pragma unroll
        for (int i = 0; i < 8; i += 2 * h) {
            #pragma unroll
            for (int k = 0; k < h; ++k) {
                float4 a = u[i + k], b = u[i + k + h];
                u[i + k] = add4(a, b);
                u[i + k + h] = sub4(a, b);
            }
        }
    }
}

// ---------------- Pass 1: bits 0..14, one ROWPAIR per 512-thread block ------
__global__ __launch_bounds__(512) void fwht_low15_pair2(
        const float* __restrict__ in, uint4* __restrict__ ws4) {
    __shared__ float4 lds4[4096];                    // 64 KB exchange region
    __shared__ uint2 stash[8192];                    // 64 KB row-A bf16 stash
    const int t = threadIdx.x;                       // 0..511
    const int rp = blockIdx.x;                       // rowpair 0..1023

    #pragma unroll
    for (int rr = 0; rr < 2; ++rr) {
        const nvf4* in4 =
            reinterpret_cast<const nvf4*>(in) + ((size_t)(2 * rp + rr) << 13);

        float4 v[16];
        #pragma unroll
        for (int k = 0; k < 16; ++k) {
            nvf4 xv = __builtin_nontemporal_load(in4 + t + 512 * k);
            float a0 = xv[0] + xv[1], a1 = xv[0] - xv[1];
            float a2 = xv[2] + xv[3], a3 = xv[2] - xv[3];
            v[k] = make_float4(a0 + a2, a1 + a3, a0 - a2, a1 - a3);
        }
        // k-ladder: quad bits 9..12 = float bits 11..14
        #pragma unroll
        for (int h = 1; h < 16; h <<= 1) {
            #pragma unroll
            for (int i = 0; i < 16; i += 2 * h) {
                #pragma unroll
                for (int k = 0; k < h; ++k) {
                    float4 a = v[i + k], b = v[i + k + h];
                    v[i + k] = add4(a, b);
                    v[i + k + h] = sub4(a, b);
                }
            }
        }

        #pragma unroll
        for (int hf = 0; hf < 2; ++hf) {
            float4* u = v + hf * 8;
            if (rr + hf) __syncthreads();            // prior ExC reads done
            #pragma unroll
            for (int k2 = 0; k2 < 8; ++k2)
                lds4[SWZ((k2 << 9) | t)] = u[k2];
            __syncthreads();

            // Exchange A: float bits 2..4
            #pragma unroll
            for (int j = 0; j < 8; ++j) u[j] = lds4[SWZ((t << 3) | j)];
            lad3(u);
            #pragma unroll
            for (int j = 0; j < 8; ++j) lds4[SWZ((t << 3) | j)] = u[j];
            __syncthreads();

            // Exchange B: float bits 5..7
            const int bB = ((t >> 3) << 6) | (t & 7);
            #pragma unroll
            for (int j = 0; j < 8; ++j) u[j] = lds4[SWZ(bB | (j << 3))];
            lad3(u);
            #pragma unroll
            for (int j = 0; j < 8; ++j) lds4[SWZ(bB | (j << 3))] = u[j];
            __syncthreads();

            // Exchange C: float bits 8..10, then pack bf16
            const int bC = ((t >> 6) << 9) | (t & 63);
            #pragma unroll
            for (int j = 0; j < 8; ++j) u[j] = lds4[SWZ(bC | (j << 6))];
            lad3(u);

            if (rr == 0) {
                #pragma unroll
                for (int j = 0; j < 8; ++j) {
                    uint2 pk;
                    pk.x = bfp(u[j].x) | (bfp(u[j].y) << 16);
                    pk.y = bfp(u[j].z) | (bfp(u[j].w) << 16);
                    stash[(hf * 8 + j) * 512 + t] = pk;
                }
            } else {
                #pragma unroll
                for (int j = 0; j < 8; ++j) {
                    uint2 pb;
                    pb.x = bfp(u[j].x) | (bfp(u[j].y) << 16);
                    pb.y = bfp(u[j].z) | (bfp(u[j].w) << 16);
                    uint2 pa = stash[(hf * 8 + j) * 512 + t];
                    uint4 o;                          // c0A c0B c1A c1B ...
                    o.x = (pa.x & 0xffffu) | (pb.x << 16);
                    o.y = (pa.x >> 16) | (pb.x & 0xffff0000u);
                    o.z = (pa.y & 0xffffu) | (pb.y << 16);
                    o.w = (pa.y >> 16) | (pb.y & 0xffff0000u);
                    const int q = (hf << 12) | bC | (j << 6);   // quad in row
                    ws4[(size_t)(q >> 3) * 8192 + rp * 8 + (q & 7)] = o;
                }
            }
        }
    }
}

// ---------------- Pass 2: bits 15..25, one cb per block ---------------------
__global__ __launch_bounds__(1024) void fwht_high11_cb(
        const unsigned int* __restrict__ ws32, float* __restrict__ out) {
    __shared__ float lds[32768];                     // 128 KB transpose buffer
    const int t = threadIdx.x;
    const int c = t & 31;
    const int g = t >> 5;                            // 0..31
    const int cb = blockIdx.x;                       // colblk 0..1023
    const unsigned int* wsb = ws32 + (size_t)cb * 32768;   // 128 KB contiguous

    // uint = {par0, par1} of (rowpair rp = g+32*jp, col c)
    float v[64];
    #pragma unroll
    for (int jp = 0; jp < 32; ++jp) {
        unsigned int u = wsb[(g + 32 * jp) * 32 + c];
        v[2 * jp]     = bf2f(u & 0xffffu);
        v[2 * jp + 1] = bf2f(u >> 16);
    }

    // Phase A: 6-bit ladder (bit0 = parity = global bit 15, bits 1..5 = 21..25)
    #pragma unroll
    for (int h = 1; h < 64; h <<= 1) {
        #pragma unroll
        for (int i = 0; i < 64; i += 2 * h) {
            #pragma unroll
            for (int k = 0; k < h; ++k) {
                float a = v[i + k], b = v[i + k + h];
                v[i + k] = a + b;
                v[i + k + h] = a - b;
            }
        }
    }

    // Transpose chunks; phase B: 5-bit ladder over s (global bits 16..20)
    #pragma unroll
    for (int m = 0; m < 2; ++m) {
        if (m) __syncthreads();
        #pragma unroll
        for (int jj = 0; jj < 32; ++jj)
            lds[jj * 1024 + g * 32 + c] = v[32 * m + jj];   // bank = c, free
        __syncthreads();

        float w[32];
        #pragma unroll
        for (int s = 0; s < 32; ++s)
            w[s] = lds[g * 1024 + s * 32 + c];
        #pragma unroll
        for (int h = 1; h < 32; h <<= 1) {
            #pragma unroll
            for (int i = 0; i < 32; i += 2 * h) {
                #pragma unroll
                for (int k = 0; k < h; ++k) {
                    float a = w[i + k], b = w[i + k + h];
                    w[i + k] = a + b;
                    w[i + k + h] = a - b;
                }
            }
        }
        const int rbase = 1024 * m + 32 * (g & ~1) + (g & 1);
        #pragma unroll
        for (int s = 0; s < 32; ++s)
            __builtin_nontemporal_store(
                w[s], &out[((size_t)(rbase + 2 * s) << 15) + (size_t)cb * 32 + c]);
    }
}

// ---------------- Fallback: proven all-fp32 2-pass path (R6) ----------------
__global__ __launch_bounds__(512) void fwht_low15_f32(const float* __restrict__ in,
                                                      float* __restrict__ out) {
    __shared__ float4 lds4[4096];
    const int t = threadIdx.x;
    const size_t base4 = (size_t)blockIdx.x * 8192;
    const nvf4* in4 = reinterpret_cast<const nvf4*>(in) + base4;
    float4* out4 = reinterpret_cast<float4*>(out) + base4;
    float4 v[16];
    #pragma unroll
    for (int k = 0; k < 16; ++k) {
        nvf4 xv = __builtin_nontemporal_load(in4 + t + 512 * k);
        float a0 = xv[0] + xv[1], a1 = xv[0] - xv[1];
        float a2 = xv[2] + xv[3], a3 = xv[2] - xv[3];
        v[k] = make_float4(a0 + a2, a1 + a3, a0 - a2, a1 - a3);
    }
    #pragma unroll
    for (int h = 1; h < 16; h <<= 1) {
        #pragma unroll
        for (int i = 0; i < 16; i += 2 * h) {
            #pragma unroll
            for (int k = 0; k < h; ++k) {
                float4 a = v[i + k], b = v[i + k + h];
                v[i + k] = add4(a, b);
                v[i + k + h] = sub4(a, b);
            }
        }
    }
    #pragma unroll
    for (int hf = 0; hf < 2; ++hf) {
        float4* u = v + hf * 8;
        if (hf) __syncthreads();
        #pragma unroll
        for (int k2 = 0; k2 < 8; ++k2) lds4[SWZ((k2 << 9) | t)] = u[k2];
        __syncthreads();
        #pragma unroll
        for (int j = 0; j < 8; ++j) u[j] = lds4[SWZ((t << 3) | j)];
        lad3(u);
        #pragma unroll
        for (int j = 0; j < 8; ++j) lds4[SWZ((t << 3) | j)] = u[j];
        __syncthreads();
        const int bB = ((t >> 3) << 6) | (t & 7);
        #pragma unroll
        for (int j = 0; j < 8; ++j) u[j] = lds4[SWZ(bB | (j << 3))];
        lad3(u);
        #pragma unroll
        for (int j = 0; j < 8; ++j) lds4[SWZ(bB | (j << 3))] = u[j];
        __syncthreads();
        const int bC = ((t >> 6) << 9) | (t & 63);
        #pragma unroll
        for (int j = 0; j < 8; ++j) u[j] = lds4[SWZ(bC | (j << 6))];
        lad3(u);
        #pragma unroll
        for (int j = 0; j < 8; ++j) out4[(hf << 12) | bC | (j << 6)] = u[j];
    }
}

__global__ __launch_bounds__(1024) void fwht_high11_f32(float* __restrict__ data) {
    __shared__ float lds[32768];
    const int t = threadIdx.x;
    const int c = t & 31;
    const int g = t >> 5;
    const size_t col = (size_t)blockIdx.x * 32 + c;
    float v[64];
    #pragma unroll
    for (int j = 0; j < 64; ++j)
        v[j] = data[((size_t)(g + 32 * j) << 15) + col];
    #pragma unroll
    for (int h = 1; h < 64; h <<= 1) {
        #pragma unroll
        for (int i = 0; i < 64; i += 2 * h) {
            #pragma unroll
            for (int k = 0; k < h; ++k) {
                float a = v[i + k], b = v[i + k + h];
                v[i + k] = a + b;
                v[i + k + h] = a - b;
            }
        }
    }
    #pragma unroll
    for (int m = 0; m < 2; ++m) {
        if (m) __syncthreads();
        #pragma unroll
        for (int jj = 0; jj < 32; ++jj)
            lds[jj * 1024 + g * 32 + c] = v[32 * m + jj];
        __syncthreads();
        float w[32];
        #pragma unroll
        for (int s = 0; s < 32; ++s) w[s] = lds[g * 1024 + s * 32 + c];
        #pragma unroll
        for (int h = 1; h < 32; h <<= 1) {
            #pragma unroll
            for (int i = 0; i < 32; i += 2 * h) {
                #pragma unroll
                for (int k = 0; k < h; ++k) {
                    float a = w[i + k], b = w[i + k + h];
                    w[i + k] = a + b;
                    w[i + k + h] = a - b;
                }
            }
        }
        const int rowbase = 32 * (32 * m + g);
        #pragma unroll
        for (int s = 0; s < 32; ++s)
            data[((size_t)(rowbase + s) << 15) + col] = w[s];
    }
}

extern "C" void kernel_launch(void* const* d_in, const int* in_sizes, int n_in,
                              void* d_out, int out_size, void* d_ws, size_t ws_size,
                              hipStream_t stream) {
    const float* x = (const float*)d_in[0];
    float* out = (float*)d_out;
    const size_t need = (size_t)1 << 27;             // 128 MB bf16 intermediate
    if (ws_size >= need && d_ws != nullptr) {
        fwht_low15_pair2<<<1024, 512, 0, stream>>>(x, (uint4*)d_ws);
        fwht_high11_cb<<<1024, 1024, 0, stream>>>((const unsigned int*)d_ws, out);
    } else {
        fwht_low15_f32<<<2048, 512, 0, stream>>>(x, out);
        fwht_high11_f32<<<1024, 1024, 0, stream>>>(out);
    }
}